// Round 2
// baseline (885.275 us; speedup 1.0000x reference)
//
#include <hip/hip_runtime.h>

#define N0v 614400
#define N1v 40960
#define BATCHv 4096

typedef __attribute__((ext_vector_type(8))) short short8;
typedef __attribute__((ext_vector_type(4))) float floatx4;

static __device__ __forceinline__ float flog1p(float v) { return __logf(v + 1.0f); }
static __device__ __forceinline__ float sigf(float v) { return 1.0f / (1.0f + __expf(-v)); }
static __device__ __forceinline__ float tanhfast(float v) {
    return 1.0f - 2.0f / (__expf(2.0f * v) + 1.0f);
}
static __device__ __forceinline__ unsigned short f2bf(float f) {
    union { float f; unsigned u; } v; v.f = f;
    unsigned r = v.u + 0x7FFFu + ((v.u >> 16) & 1u);   // RNE
    return (unsigned short)(r >> 16);
}
static __device__ __forceinline__ float bf2f(unsigned short u) {
    return __uint_as_float(((unsigned)u) << 16);
}

// ---------------------------------------------------------------------------
// Weight pre-convert: fp32 -> bf16 copies in ws, plus bsum = b_ih + b_hh.
// ---------------------------------------------------------------------------
__global__ __launch_bounds__(256) void cvt_weights_kernel(
    const float* __restrict__ Wp, const float* __restrict__ Ws0,
    const float* __restrict__ Wn0, const float* __restrict__ Wih,
    const float* __restrict__ Whh, const float* __restrict__ bih,
    const float* __restrict__ bhh,
    unsigned short* __restrict__ Wpb, unsigned short* __restrict__ Ws0b,
    unsigned short* __restrict__ Wn0b, unsigned short* __restrict__ Wihb,
    unsigned short* __restrict__ Whhb, float* __restrict__ bsum)
{
    const int g = blockIdx.x * 256 + threadIdx.x;
    if (g < 16384)            Wpb[g] = f2bf(Wp[g]);
    else if (g < 49152)       Ws0b[g - 16384] = f2bf(Ws0[g - 16384]);
    else if (g < 81920)       Wn0b[g - 49152] = f2bf(Wn0[g - 49152]);
    else if (g < 344064)      Wihb[g - 81920] = f2bf(Wih[g - 81920]);
    else if (g < 606208)      Whhb[g - 344064] = f2bf(Whh[g - 344064]);
    else if (g < 607232) { const int i = g - 606208; bsum[i] = bih[i] + bhh[i]; }
}

// ---------------------------------------------------------------------------
// Stage A: pool-SAGE. Per block: 4 groups (60 gathered rows + 4 pad) x 128 cols,
// K=128 (2 staged chunks of 64). MFMA 16x16x32 bf16. relu+max epilogue via LDS
// atomicMax (uint-punned, vals >= 0). Output bf16.
// ---------------------------------------------------------------------------
__global__ __launch_bounds__(256) void pool_max_kernel(
    const float* __restrict__ x, const int* __restrict__ nbr0,
    const unsigned short* __restrict__ Wpb, const float* __restrict__ bp,
    unsigned short* __restrict__ hnb)
{
    __shared__ unsigned short smem[64 * 72 + 128 * 72];
    __shared__ unsigned red[512];
    __shared__ int nodes[64];
    unsigned short* aT = smem;
    unsigned short* wT = smem + 64 * 72;

    const int tid = threadIdx.x;
    const size_t base = (size_t)blockIdx.x * 60;
    if (tid < 64) nodes[tid] = (tid < 60) ? nbr0[base + tid] : 0;
    for (int i = tid; i < 512; i += 256) red[i] = 0u;

    const int lane = tid & 63, wv = tid >> 6;
    const int ml = lane & 15, q = lane >> 4, qk = q * 8;

    floatx4 acc[8];
#pragma unroll
    for (int ct = 0; ct < 8; ++ct) acc[ct] = (floatx4){0.f, 0.f, 0.f, 0.f};

    for (int kc = 0; kc < 2; ++kc) {
        __syncthreads();
        for (int i = tid; i < 512; i += 256) {            // A: 64 rows x 64 k
            const int row = i >> 3, seg = i & 7;
            short8 o = {0, 0, 0, 0, 0, 0, 0, 0};
            if (row < 60) {
                const float* s = x + (size_t)nodes[row] * 128 + kc * 64 + seg * 8;
                const float4 f0 = *(const float4*)s;
                const float4 f1 = *(const float4*)(s + 4);
                o[0] = (short)f2bf(flog1p(f0.x)); o[1] = (short)f2bf(flog1p(f0.y));
                o[2] = (short)f2bf(flog1p(f0.z)); o[3] = (short)f2bf(flog1p(f0.w));
                o[4] = (short)f2bf(flog1p(f1.x)); o[5] = (short)f2bf(flog1p(f1.y));
                o[6] = (short)f2bf(flog1p(f1.z)); o[7] = (short)f2bf(flog1p(f1.w));
            }
            *(short8*)&aT[row * 72 + seg * 8] = o;
        }
        for (int i = tid; i < 1024; i += 256) {           // W: 128 rows x 64 k
            const int row = i >> 3, seg = i & 7;
            *(short8*)&wT[row * 72 + seg * 8] =
                *(const short8*)&Wpb[(size_t)row * 128 + kc * 64 + seg * 8];
        }
        __syncthreads();
#pragma unroll
        for (int k0 = 0; k0 < 64; k0 += 32) {
            const short8 a = *(const short8*)&aT[(wv * 16 + ml) * 72 + k0 + qk];
#pragma unroll
            for (int ct = 0; ct < 8; ++ct) {
                const short8 b = *(const short8*)&wT[(ct * 16 + ml) * 72 + k0 + qk];
                acc[ct] = __builtin_amdgcn_mfma_f32_16x16x32_bf16(a, b, acc[ct], 0, 0, 0);
            }
        }
    }
    __syncthreads();
#pragma unroll
    for (int ct = 0; ct < 8; ++ct) {
        const int col = ct * 16 + ml;
        const float bb = bp[col];
#pragma unroll
        for (int r = 0; r < 4; ++r) {
            const int row = wv * 16 + q * 4 + r;
            if (row < 60) {
                const float v = fmaxf(acc[ct][r] + bb, 0.0f);
                atomicMax(&red[(row / 15) * 128 + col], __float_as_uint(v));
            }
        }
    }
    __syncthreads();
    for (int i = tid; i < 512; i += 256)
        hnb[(size_t)blockIdx.x * 512 + i] = f2bf(__uint_as_float(red[i]));
}

// ---------------------------------------------------------------------------
// Stage B: h0 = [log1p(x[:N1]) | h_neigh] @ [Ws0|Wn0]^T + b0, stored bf16 (pre-BN),
// with fused per-column sum/sumsq partials.
// ---------------------------------------------------------------------------
__global__ __launch_bounds__(256) void h0_kernel(
    const float* __restrict__ x, const unsigned short* __restrict__ hnb,
    const unsigned short* __restrict__ Ws0b, const unsigned short* __restrict__ Wn0b,
    const float* __restrict__ b0, unsigned short* __restrict__ h0bf,
    float* __restrict__ bn_sum, float* __restrict__ bn_sq)
{
    __shared__ unsigned short smem[64 * 72 + 128 * 72];
    unsigned short* aT = smem;
    unsigned short* wT = smem + 64 * 72;

    const int tid = threadIdx.x;
    const int m0 = blockIdx.x * 64, c0 = blockIdx.y * 128;
    const int lane = tid & 63, wv = tid >> 6;
    const int ml = lane & 15, q = lane >> 4, qk = q * 8;

    floatx4 acc[8];
#pragma unroll
    for (int ct = 0; ct < 8; ++ct) acc[ct] = (floatx4){0.f, 0.f, 0.f, 0.f};

    for (int kc = 0; kc < 4; ++kc) {
        __syncthreads();
        for (int i = tid; i < 512; i += 256) {
            const int row = i >> 3, seg = i & 7;
            const int k = kc * 64 + seg * 8;
            if (kc < 2) {
                const float* s = x + (size_t)(m0 + row) * 128 + k;
                const float4 f0 = *(const float4*)s;
                const float4 f1 = *(const float4*)(s + 4);
                short8 o;
                o[0] = (short)f2bf(flog1p(f0.x)); o[1] = (short)f2bf(flog1p(f0.y));
                o[2] = (short)f2bf(flog1p(f0.z)); o[3] = (short)f2bf(flog1p(f0.w));
                o[4] = (short)f2bf(flog1p(f1.x)); o[5] = (short)f2bf(flog1p(f1.y));
                o[6] = (short)f2bf(flog1p(f1.z)); o[7] = (short)f2bf(flog1p(f1.w));
                *(short8*)&aT[row * 72 + seg * 8] = o;
            } else {
                *(short8*)&aT[row * 72 + seg * 8] =
                    *(const short8*)&hnb[(size_t)(m0 + row) * 128 + (k - 128)];
            }
        }
        for (int i = tid; i < 1024; i += 256) {
            const int row = i >> 3, seg = i & 7;
            const int k = kc * 64 + seg * 8;
            const size_t cg = (size_t)(c0 + row);
            *(short8*)&wT[row * 72 + seg * 8] = (kc < 2)
                ? *(const short8*)&Ws0b[cg * 128 + k]
                : *(const short8*)&Wn0b[cg * 128 + (k - 128)];
        }
        __syncthreads();
#pragma unroll
        for (int k0 = 0; k0 < 64; k0 += 32) {
            const short8 a = *(const short8*)&aT[(wv * 16 + ml) * 72 + k0 + qk];
#pragma unroll
            for (int ct = 0; ct < 8; ++ct) {
                const short8 b = *(const short8*)&wT[(ct * 16 + ml) * 72 + k0 + qk];
                acc[ct] = __builtin_amdgcn_mfma_f32_16x16x32_bf16(a, b, acc[ct], 0, 0, 0);
            }
        }
    }
    __syncthreads();
    float* scr = (float*)smem;   // 4096 floats = 16 KB
#pragma unroll
    for (int ct = 0; ct < 8; ++ct) {
        const int col = ct * 16 + ml, cg = c0 + col;
        const float bb = b0[cg];
        float s = 0.f, sq = 0.f;
#pragma unroll
        for (int r = 0; r < 4; ++r) {
            const int row = wv * 16 + q * 4 + r;
            const float v = acc[ct][r] + bb;
            h0bf[(size_t)(m0 + row) * 256 + cg] = f2bf(v);
            s += v; sq += v * v;
        }
        scr[(wv * 4 + q) * 128 + col] = s;
        scr[2048 + (wv * 4 + q) * 128 + col] = sq;
    }
    __syncthreads();
    if (tid < 128) {
        float s = 0.f, sq = 0.f;
#pragma unroll
        for (int j = 0; j < 16; ++j) {
            s += scr[j * 128 + tid];
            sq += scr[2048 + j * 128 + tid];
        }
        atomicAdd(&bn_sum[c0 + tid], s);
        atomicAdd(&bn_sq[c0 + tid], sq);
    }
}

__global__ void bn_stats_kernel(const float* __restrict__ bn_sum, const float* __restrict__ bn_sq,
                                const float* __restrict__ gamma, const float* __restrict__ beta,
                                float* __restrict__ scale, float* __restrict__ shift)
{
    const int c = threadIdx.x;   // 256
    const float inv_n = 1.0f / (float)N1v;
    const float mu = bn_sum[c] * inv_n;
    const float var = bn_sq[c] * inv_n - mu * mu;
    const float rs = rsqrtf(var + 1e-5f);
    const float sc = rs * gamma[c];
    scale[c] = sc;
    shift[c] = beta[c] - mu * sc;
}

// ---------------------------------------------------------------------------
// Persistent LSTM: ALL 10 steps + final output GEMM in one kernel.
// 128 blocks x 512 threads (8 waves). Each block owns 32 batch rows and ALL
// 1024 gate columns (wave wv: gate-interleaved h-cols [wv*32, wv*32+32) for
// all 4 gates -> pointwise LSTM entirely in registers; c-state in registers).
// A-tile in LDS: 32 rows x 520 (= [gathered h0n+BN (k 0..255) | h_prev (k
// 256..511)] + 8 pad). The step epilogue writes h (bf16) directly into the
// A-tile's upper K half for the next step. BN+relu applied on the fly when
// reading h0bf (bit-identical to old bn_apply). B-fragments are read directly
// from L2 (weights = 1 MB, L2-resident) with a 1-deep register prefetch.
// t=0 skips the h_prev K-half (h==0). Tail: out = [self_bn | hT] @ [Ws1|Wn1]^T
// + b1 using fp32 weights, A read from LDS (broadcast).
// ---------------------------------------------------------------------------
__global__ __launch_bounds__(512, 2) void lstm_persist_kernel(
    const unsigned short* __restrict__ h0bf, const int* __restrict__ nbr1,
    const unsigned short* __restrict__ Wihb, const unsigned short* __restrict__ Whhb,
    const float* __restrict__ bsum, const float* __restrict__ bn_scale,
    const float* __restrict__ bn_shift, const float* __restrict__ Ws1,
    const float* __restrict__ Wn1, const float* __restrict__ b1,
    float* __restrict__ out)
{
    __shared__ unsigned short aT[32 * 520];   // 33,280 B
    __shared__ float sc[256], sh[256];
    __shared__ int nodes[32];

    const int tid = threadIdx.x;
    const int m0 = blockIdx.x * 32;
    const int lane = tid & 63, wv = tid >> 6;          // wv 0..7
    const int ml = lane & 15, q = lane >> 4, qk = q * 8;

    if (tid < 256) { sc[tid] = bn_scale[tid]; sh[tid] = bn_shift[tid]; }

    // per-thread constant W element offsets (8 gate-col tiles)
    int wroff[8];
#pragma unroll
    for (int ct = 0; ct < 8; ++ct)
        wroff[ct] = ((ct >> 1) * 256 + wv * 32 + (ct & 1) * 16 + ml) * 256;

    // biases per (gate, hg)
    float bias[4][2];
#pragma unroll
    for (int g = 0; g < 4; ++g)
#pragma unroll
        for (int hg = 0; hg < 2; ++hg)
            bias[g][hg] = bsum[g * 256 + wv * 32 + hg * 16 + ml];

    // c-state in registers: cs[rt][hg][r]
    float cs[2][2][4];
#pragma unroll
    for (int rt = 0; rt < 2; ++rt)
#pragma unroll
        for (int hg = 0; hg < 2; ++hg)
#pragma unroll
            for (int r = 0; r < 4; ++r) cs[rt][hg][r] = 0.f;

    for (int t = 0; t < 10; ++t) {
        if (tid < 32) nodes[tid] = nbr1[(size_t)(m0 + tid) * 10 + t];
        __syncthreads();                                   // S1: nodes + prev h visible
        // stage gathered rows with BN+relu into A cols 0..255
        for (int i = tid; i < 1024; i += 512) {            // 32 rows x 32 segs
            const int row = i >> 5, seg = i & 31;
            const short8 v = *(const short8*)&h0bf[(size_t)nodes[row] * 256 + seg * 8];
            short8 o;
#pragma unroll
            for (int j = 0; j < 8; ++j) {
                const float f = fmaxf(fmaf(bf2f((unsigned short)v[j]),
                                           sc[seg * 8 + j], sh[seg * 8 + j]), 0.0f);
                o[j] = (short)f2bf(f);
            }
            *(short8*)&aT[row * 520 + seg * 8] = o;
        }
        __syncthreads();                                   // S2: A-tile ready

        floatx4 acc[2][8];
#pragma unroll
        for (int rt = 0; rt < 2; ++rt)
#pragma unroll
            for (int ct = 0; ct < 8; ++ct) acc[rt][ct] = (floatx4){0.f, 0.f, 0.f, 0.f};

        const int ksN = (t == 0) ? 8 : 16;                 // t=0: h_prev == 0
        short8 bcur[8], bnxt[8];
#pragma unroll
        for (int ct = 0; ct < 8; ++ct)
            bcur[ct] = *(const short8*)&Wihb[wroff[ct] + qk];
        for (int ks = 0; ks < ksN; ++ks) {
            const int ksn = ks + 1;
            if (ksn < ksN) {                               // 1-deep B prefetch (L2)
                const unsigned short* wb = (ksn < 8) ? Wihb : Whhb;
                const int koff = (ksn & 7) * 32 + qk;
#pragma unroll
                for (int ct = 0; ct < 8; ++ct)
                    bnxt[ct] = *(const short8*)&wb[wroff[ct] + koff];
            }
            const short8 a0 = *(const short8*)&aT[ml * 520 + ks * 32 + qk];
            const short8 a1 = *(const short8*)&aT[(16 + ml) * 520 + ks * 32 + qk];
#pragma unroll
            for (int ct = 0; ct < 8; ++ct) {
                acc[0][ct] = __builtin_amdgcn_mfma_f32_16x16x32_bf16(a0, bcur[ct], acc[0][ct], 0, 0, 0);
                acc[1][ct] = __builtin_amdgcn_mfma_f32_16x16x32_bf16(a1, bcur[ct], acc[1][ct], 0, 0, 0);
            }
#pragma unroll
            for (int ct = 0; ct < 8; ++ct) bcur[ct] = bnxt[ct];
        }

        // pointwise LSTM in registers
        unsigned short hv[2][2][4];
#pragma unroll
        for (int rt = 0; rt < 2; ++rt)
#pragma unroll
            for (int hg = 0; hg < 2; ++hg)
#pragma unroll
                for (int r = 0; r < 4; ++r) {
                    const float gi = acc[rt][0 + hg][r] + bias[0][hg];
                    const float gf = acc[rt][2 + hg][r] + bias[1][hg];
                    const float gg = acc[rt][4 + hg][r] + bias[2][hg];
                    const float go = acc[rt][6 + hg][r] + bias[3][hg];
                    float c = sigf(gi) * tanhfast(gg);
                    if (t > 0) c += sigf(gf) * cs[rt][hg][r];
                    cs[rt][hg][r] = c;
                    hv[rt][hg][r] = f2bf(sigf(go) * tanhfast(c));
                }
        __syncthreads();                                   // S3: all A reads done
#pragma unroll
        for (int rt = 0; rt < 2; ++rt)
#pragma unroll
            for (int hg = 0; hg < 2; ++hg)
#pragma unroll
                for (int r = 0; r < 4; ++r)
                    aT[(rt * 16 + q * 4 + r) * 520 + 256 + wv * 32 + hg * 16 + ml] =
                        hv[rt][hg][r];
        // next iteration's S1 orders these h-writes before the MFMA reads
    }

    // ---- tail: out = [self_bn | hT] @ [Ws1 | Wn1]^T + b1  (32 x 32) ----
    // stage BN'd self rows (m0..m0+31) into A cols 0..255 (hT already in 256..511)
    for (int i = tid; i < 1024; i += 512) {
        const int row = i >> 5, seg = i & 31;
        const short8 v = *(const short8*)&h0bf[(size_t)(m0 + row) * 256 + seg * 8];
        short8 o;
#pragma unroll
        for (int j = 0; j < 8; ++j) {
            const float f = fmaxf(fmaf(bf2f((unsigned short)v[j]),
                                       sc[seg * 8 + j], sh[seg * 8 + j]), 0.0f);
            o[j] = (short)f2bf(f);
        }
        *(short8*)&aT[row * 520 + seg * 8] = o;
    }
    __syncthreads();

    for (int e = tid; e < 1024; e += 512) {
        const int row = e >> 5, cls = e & 31;
        const float* w0 = Ws1 + (size_t)cls * 256;
        const float* w1 = Wn1 + (size_t)cls * 256;
        const unsigned short* ar = &aT[row * 520];
        float s = b1[cls];
#pragma unroll 4
        for (int k8 = 0; k8 < 32; ++k8) {
            const short8 av = *(const short8*)&ar[k8 * 8];
            const short8 bv = *(const short8*)&ar[256 + k8 * 8];
            const float4 wa0 = *(const float4*)&w0[k8 * 8];
            const float4 wa1 = *(const float4*)&w0[k8 * 8 + 4];
            const float4 wb0 = *(const float4*)&w1[k8 * 8];
            const float4 wb1 = *(const float4*)&w1[k8 * 8 + 4];
            s += bf2f((unsigned short)av[0]) * wa0.x + bf2f((unsigned short)av[1]) * wa0.y;
            s += bf2f((unsigned short)av[2]) * wa0.z + bf2f((unsigned short)av[3]) * wa0.w;
            s += bf2f((unsigned short)av[4]) * wa1.x + bf2f((unsigned short)av[5]) * wa1.y;
            s += bf2f((unsigned short)av[6]) * wa1.z + bf2f((unsigned short)av[7]) * wa1.w;
            s += bf2f((unsigned short)bv[0]) * wb0.x + bf2f((unsigned short)bv[1]) * wb0.y;
            s += bf2f((unsigned short)bv[2]) * wb0.z + bf2f((unsigned short)bv[3]) * wb0.w;
            s += bf2f((unsigned short)bv[4]) * wb1.x + bf2f((unsigned short)bv[5]) * wb1.y;
            s += bf2f((unsigned short)bv[6]) * wb1.z + bf2f((unsigned short)bv[7]) * wb1.w;
        }
        out[(size_t)(m0 + row) * 32 + cls] = s;
    }
}

extern "C" void kernel_launch(void* const* d_in, const int* in_sizes, int n_in,
                              void* d_out, int out_size, void* d_ws, size_t ws_size,
                              hipStream_t stream)
{
    const float* x        = (const float*)d_in[0];
    const int*   nbr0     = (const int*)d_in[1];
    const int*   nbr1     = (const int*)d_in[2];
    const float* W_pool   = (const float*)d_in[3];
    const float* b_pool   = (const float*)d_in[4];
    const float* W_self0  = (const float*)d_in[5];
    const float* W_neigh0 = (const float*)d_in[6];
    const float* b0       = (const float*)d_in[7];
    const float* gamma0   = (const float*)d_in[8];
    const float* beta0    = (const float*)d_in[9];
    const float* W_ih     = (const float*)d_in[10];
    const float* W_hh     = (const float*)d_in[11];
    const float* b_ih     = (const float*)d_in[12];
    const float* b_hh     = (const float*)d_in[13];
    const float* W_self1  = (const float*)d_in[14];
    const float* W_neigh1 = (const float*)d_in[15];
    const float* b1       = (const float*)d_in[16];
    float* out = (float*)d_out;

    // ws layout (bytes). h0nbf/cst/hb0/hb1/gbuf all removed (persistent LSTM
    // keeps c in registers and h in LDS; BN folded into h0bf consumers).
    char* ws = (char*)d_ws;
    unsigned short* h0bf  = (unsigned short*)(ws);               // 20,971,520 B
    unsigned short* hnb   = (unsigned short*)(ws + 20971520);    // 10,485,760 B
    unsigned short* Wpb   = (unsigned short*)(ws + 60817408);    //     32,768 B
    unsigned short* Ws0b  = (unsigned short*)(ws + 60850176);    //     65,536 B
    unsigned short* Wn0b  = (unsigned short*)(ws + 60915712);    //     65,536 B
    unsigned short* Wihb  = (unsigned short*)(ws + 60981248);    //    524,288 B
    unsigned short* Whhb  = (unsigned short*)(ws + 61505536);    //    524,288 B
    float*          bsum  = (float*)(ws + 62029824);             //      4,096 B
    float*          bn_sum   = (float*)(ws + 62033920);
    float*          bn_sq    = (float*)(ws + 62034944);
    float*          bn_scale = (float*)(ws + 62035968);
    float*          bn_shift = (float*)(ws + 62036992);

    hipMemsetAsync(bn_sum, 0, 2048, stream);        // bn_sum + bn_sq

    cvt_weights_kernel<<<2372, 256, 0, stream>>>(W_pool, W_self0, W_neigh0, W_ih, W_hh,
                                                 b_ih, b_hh, Wpb, Ws0b, Wn0b, Wihb, Whhb, bsum);
    pool_max_kernel<<<N1v / 4, 256, 0, stream>>>(x, nbr0, Wpb, b_pool, hnb);
    h0_kernel<<<dim3(N1v / 64, 2), 256, 0, stream>>>(x, hnb, Ws0b, Wn0b, b0,
                                                     h0bf, bn_sum, bn_sq);
    bn_stats_kernel<<<1, 256, 0, stream>>>(bn_sum, bn_sq, gamma0, beta0, bn_scale, bn_shift);
    lstm_persist_kernel<<<BATCHv / 32, 512, 0, stream>>>(
        h0bf, nbr1, Wihb, Whhb, bsum, bn_scale, bn_shift, W_self1, W_neigh1, b1, out);
}

// Round 3
// 797.445 us; speedup vs baseline: 1.1101x; 1.1101x over previous
//
#include <hip/hip_runtime.h>

#define N0v 614400
#define N1v 40960
#define BATCHv 4096

typedef __attribute__((ext_vector_type(8))) short short8;
typedef __attribute__((ext_vector_type(4))) float floatx4;

static __device__ __forceinline__ float flog1p(float v) { return __logf(v + 1.0f); }
static __device__ __forceinline__ float sigf(float v) { return 1.0f / (1.0f + __expf(-v)); }
static __device__ __forceinline__ float tanhfast(float v) {
    return 1.0f - 2.0f / (__expf(2.0f * v) + 1.0f);
}
static __device__ __forceinline__ unsigned short f2bf(float f) {
    union { float f; unsigned u; } v; v.f = f;
    unsigned r = v.u + 0x7FFFu + ((v.u >> 16) & 1u);   // RNE
    return (unsigned short)(r >> 16);
}
static __device__ __forceinline__ float bf2f(unsigned short u) {
    return __uint_as_float(((unsigned)u) << 16);
}

// ---------------------------------------------------------------------------
// Weight pre-convert: fp32 -> bf16 copies in ws, plus bsum = b_ih + b_hh.
// ---------------------------------------------------------------------------
__global__ __launch_bounds__(256) void cvt_weights_kernel(
    const float* __restrict__ Wp, const float* __restrict__ Ws0,
    const float* __restrict__ Wn0, const float* __restrict__ Wih,
    const float* __restrict__ Whh, const float* __restrict__ bih,
    const float* __restrict__ bhh,
    unsigned short* __restrict__ Wpb, unsigned short* __restrict__ Ws0b,
    unsigned short* __restrict__ Wn0b, unsigned short* __restrict__ Wihb,
    unsigned short* __restrict__ Whhb, float* __restrict__ bsum)
{
    const int g = blockIdx.x * 256 + threadIdx.x;
    if (g < 16384)            Wpb[g] = f2bf(Wp[g]);
    else if (g < 49152)       Ws0b[g - 16384] = f2bf(Ws0[g - 16384]);
    else if (g < 81920)       Wn0b[g - 49152] = f2bf(Wn0[g - 49152]);
    else if (g < 344064)      Wihb[g - 81920] = f2bf(Wih[g - 81920]);
    else if (g < 606208)      Whhb[g - 344064] = f2bf(Whh[g - 344064]);
    else if (g < 607232) { const int i = g - 606208; bsum[i] = bih[i] + bhh[i]; }
}

// ---------------------------------------------------------------------------
// Stage A: pool-SAGE. Per block: 8 nodes (120 gathered rows + 8 pad) x 128 cols,
// K=128 (2 staged chunks of 64). 128-row MFMA tile: 4 waves x 2 row-tiles.
// relu+max epilogue via LDS atomicMax (uint-punned, vals >= 0). Output bf16.
// vs R1: rows/block doubled -> half the blocks, half the W-staging and
// barriers per gathered row.
// ---------------------------------------------------------------------------
__global__ __launch_bounds__(256) void pool_max_kernel(
    const float* __restrict__ x, const int* __restrict__ nbr0,
    const unsigned short* __restrict__ Wpb, const float* __restrict__ bp,
    unsigned short* __restrict__ hnb)
{
    __shared__ unsigned short smem[128 * 72 + 128 * 72];   // 36,864 B
    __shared__ unsigned red[1024];                         //  4,096 B
    __shared__ int nodes[128];
    unsigned short* aT = smem;
    unsigned short* wT = smem + 128 * 72;

    const int tid = threadIdx.x;
    const size_t base = (size_t)blockIdx.x * 120;
    if (tid < 128) nodes[tid] = (tid < 120) ? nbr0[base + tid] : 0;
    for (int i = tid; i < 1024; i += 256) red[i] = 0u;

    const int lane = tid & 63, wv = tid >> 6;              // wv 0..3
    const int ml = lane & 15, q = lane >> 4, qk = q * 8;

    floatx4 acc[2][8];
#pragma unroll
    for (int rt = 0; rt < 2; ++rt)
#pragma unroll
        for (int ct = 0; ct < 8; ++ct) acc[rt][ct] = (floatx4){0.f, 0.f, 0.f, 0.f};

    for (int kc = 0; kc < 2; ++kc) {
        __syncthreads();
        for (int i = tid; i < 1024; i += 256) {            // A: 128 rows x 64 k
            const int row = i >> 3, seg = i & 7;
            short8 o = {0, 0, 0, 0, 0, 0, 0, 0};
            if (row < 120) {
                const float* s = x + (size_t)nodes[row] * 128 + kc * 64 + seg * 8;
                const float4 f0 = *(const float4*)s;
                const float4 f1 = *(const float4*)(s + 4);
                o[0] = (short)f2bf(flog1p(f0.x)); o[1] = (short)f2bf(flog1p(f0.y));
                o[2] = (short)f2bf(flog1p(f0.z)); o[3] = (short)f2bf(flog1p(f0.w));
                o[4] = (short)f2bf(flog1p(f1.x)); o[5] = (short)f2bf(flog1p(f1.y));
                o[6] = (short)f2bf(flog1p(f1.z)); o[7] = (short)f2bf(flog1p(f1.w));
            }
            *(short8*)&aT[row * 72 + seg * 8] = o;
        }
        for (int i = tid; i < 1024; i += 256) {            // W: 128 rows x 64 k
            const int row = i >> 3, seg = i & 7;
            *(short8*)&wT[row * 72 + seg * 8] =
                *(const short8*)&Wpb[(size_t)row * 128 + kc * 64 + seg * 8];
        }
        __syncthreads();
#pragma unroll
        for (int k0 = 0; k0 < 64; k0 += 32) {
#pragma unroll
            for (int rt = 0; rt < 2; ++rt) {
                const short8 a = *(const short8*)&aT[((rt * 4 + wv) * 16 + ml) * 72 + k0 + qk];
#pragma unroll
                for (int ct = 0; ct < 8; ++ct) {
                    const short8 b = *(const short8*)&wT[(ct * 16 + ml) * 72 + k0 + qk];
                    acc[rt][ct] = __builtin_amdgcn_mfma_f32_16x16x32_bf16(a, b, acc[rt][ct], 0, 0, 0);
                }
            }
        }
    }
    __syncthreads();
#pragma unroll
    for (int rt = 0; rt < 2; ++rt)
#pragma unroll
        for (int ct = 0; ct < 8; ++ct) {
            const int col = ct * 16 + ml;
            const float bb = bp[col];
#pragma unroll
            for (int r = 0; r < 4; ++r) {
                const int row = (rt * 4 + wv) * 16 + q * 4 + r;
                if (row < 120) {
                    const float v = fmaxf(acc[rt][ct][r] + bb, 0.0f);
                    atomicMax(&red[(row / 15) * 128 + col], __float_as_uint(v));
                }
            }
        }
    __syncthreads();
    for (int i = tid; i < 1024; i += 256)
        hnb[(size_t)blockIdx.x * 1024 + i] = f2bf(__uint_as_float(red[i]));
}

// ---------------------------------------------------------------------------
// Stage B: h0 = [log1p(x[:N1]) | h_neigh] @ [Ws0|Wn0]^T + b0, stored bf16 (pre-BN),
// with fused per-column sum/sumsq partials.
// ---------------------------------------------------------------------------
__global__ __launch_bounds__(256) void h0_kernel(
    const float* __restrict__ x, const unsigned short* __restrict__ hnb,
    const unsigned short* __restrict__ Ws0b, const unsigned short* __restrict__ Wn0b,
    const float* __restrict__ b0, unsigned short* __restrict__ h0bf,
    float* __restrict__ bn_sum, float* __restrict__ bn_sq)
{
    __shared__ unsigned short smem[64 * 72 + 128 * 72];
    unsigned short* aT = smem;
    unsigned short* wT = smem + 64 * 72;

    const int tid = threadIdx.x;
    const int m0 = blockIdx.x * 64, c0 = blockIdx.y * 128;
    const int lane = tid & 63, wv = tid >> 6;
    const int ml = lane & 15, q = lane >> 4, qk = q * 8;

    floatx4 acc[8];
#pragma unroll
    for (int ct = 0; ct < 8; ++ct) acc[ct] = (floatx4){0.f, 0.f, 0.f, 0.f};

    for (int kc = 0; kc < 4; ++kc) {
        __syncthreads();
        for (int i = tid; i < 512; i += 256) {
            const int row = i >> 3, seg = i & 7;
            const int k = kc * 64 + seg * 8;
            if (kc < 2) {
                const float* s = x + (size_t)(m0 + row) * 128 + k;
                const float4 f0 = *(const float4*)s;
                const float4 f1 = *(const float4*)(s + 4);
                short8 o;
                o[0] = (short)f2bf(flog1p(f0.x)); o[1] = (short)f2bf(flog1p(f0.y));
                o[2] = (short)f2bf(flog1p(f0.z)); o[3] = (short)f2bf(flog1p(f0.w));
                o[4] = (short)f2bf(flog1p(f1.x)); o[5] = (short)f2bf(flog1p(f1.y));
                o[6] = (short)f2bf(flog1p(f1.z)); o[7] = (short)f2bf(flog1p(f1.w));
                *(short8*)&aT[row * 72 + seg * 8] = o;
            } else {
                *(short8*)&aT[row * 72 + seg * 8] =
                    *(const short8*)&hnb[(size_t)(m0 + row) * 128 + (k - 128)];
            }
        }
        for (int i = tid; i < 1024; i += 256) {
            const int row = i >> 3, seg = i & 7;
            const int k = kc * 64 + seg * 8;
            const size_t cg = (size_t)(c0 + row);
            *(short8*)&wT[row * 72 + seg * 8] = (kc < 2)
                ? *(const short8*)&Ws0b[cg * 128 + k]
                : *(const short8*)&Wn0b[cg * 128 + (k - 128)];
        }
        __syncthreads();
#pragma unroll
        for (int k0 = 0; k0 < 64; k0 += 32) {
            const short8 a = *(const short8*)&aT[(wv * 16 + ml) * 72 + k0 + qk];
#pragma unroll
            for (int ct = 0; ct < 8; ++ct) {
                const short8 b = *(const short8*)&wT[(ct * 16 + ml) * 72 + k0 + qk];
                acc[ct] = __builtin_amdgcn_mfma_f32_16x16x32_bf16(a, b, acc[ct], 0, 0, 0);
            }
        }
    }
    __syncthreads();
    float* scr = (float*)smem;   // 4096 floats = 16 KB
#pragma unroll
    for (int ct = 0; ct < 8; ++ct) {
        const int col = ct * 16 + ml, cg = c0 + col;
        const float bb = b0[cg];
        float s = 0.f, sq = 0.f;
#pragma unroll
        for (int r = 0; r < 4; ++r) {
            const int row = wv * 16 + q * 4 + r;
            const float v = acc[ct][r] + bb;
            h0bf[(size_t)(m0 + row) * 256 + cg] = f2bf(v);
            s += v; sq += v * v;
        }
        scr[(wv * 4 + q) * 128 + col] = s;
        scr[2048 + (wv * 4 + q) * 128 + col] = sq;
    }
    __syncthreads();
    if (tid < 128) {
        float s = 0.f, sq = 0.f;
#pragma unroll
        for (int j = 0; j < 16; ++j) {
            s += scr[j * 128 + tid];
            sq += scr[2048 + j * 128 + tid];
        }
        atomicAdd(&bn_sum[c0 + tid], s);
        atomicAdd(&bn_sq[c0 + tid], sq);
    }
}

__global__ void bn_stats_kernel(const float* __restrict__ bn_sum, const float* __restrict__ bn_sq,
                                const float* __restrict__ gamma, const float* __restrict__ beta,
                                float* __restrict__ scale, float* __restrict__ shift)
{
    const int c = threadIdx.x;   // 256
    const float inv_n = 1.0f / (float)N1v;
    const float mu = bn_sum[c] * inv_n;
    const float var = bn_sq[c] * inv_n - mu * mu;
    const float rs = rsqrtf(var + 1e-5f);
    const float sc = rs * gamma[c];
    scale[c] = sc;
    shift[c] = beta[c] - mu * sc;
}

// ---------------------------------------------------------------------------
// Fused LSTM step: gates GEMM + pointwise in one kernel. BN+relu folded into
// the A-gather (reads pre-BN h0bf, applies scale/shift, rounds to bf16 ->
// bit-identical to the old bn_apply output). Gate-interleaved columns: each
// block computes all 4 gates for a 32-wide h-slice; pointwise in registers.
// K = [h0n_bn (256) | h_prev (256)]; t=0 skips the h_prev half.
// M=4096 (64/blk), h-cols 256 (32/blk via gridDim.y=8).
// ---------------------------------------------------------------------------
__global__ __launch_bounds__(256) void lstm_step_kernel(
    const unsigned short* __restrict__ h0bf, const int* __restrict__ nbr1,
    const unsigned short* __restrict__ hbprev, const unsigned short* __restrict__ Wihb,
    const unsigned short* __restrict__ Whhb, const float* __restrict__ bsum,
    const float* __restrict__ bn_scale, const float* __restrict__ bn_shift,
    float* __restrict__ cst, unsigned short* __restrict__ hb, int t)
{
    __shared__ unsigned short smem[64 * 72 + 128 * 72];
    __shared__ float scl[256], shl[256];
    __shared__ int nodes[64];
    unsigned short* aT = smem;
    unsigned short* wT = smem + 64 * 72;

    const int tid = threadIdx.x;
    const int m0 = blockIdx.x * 64, c0h = blockIdx.y * 32;
    const int lane = tid & 63, wv = tid >> 6;
    const int ml = lane & 15, q = lane >> 4, qk = q * 8;

    if (tid < 64) nodes[tid] = nbr1[(size_t)(m0 + tid) * 10 + t];
    scl[tid] = bn_scale[tid];
    shl[tid] = bn_shift[tid];

    floatx4 acc[8];
#pragma unroll
    for (int ct = 0; ct < 8; ++ct) acc[ct] = (floatx4){0.f, 0.f, 0.f, 0.f};

    const int kcN = (t == 0) ? 4 : 8;   // h_prev == 0 at t=0
    for (int kc = 0; kc < kcN; ++kc) {
        __syncthreads();
        for (int i = tid; i < 512; i += 256) {
            const int row = i >> 3, seg = i & 7;
            const int k = kc * 64 + seg * 8;
            if (kc < 4) {
                const short8 v = *(const short8*)&h0bf[(size_t)nodes[row] * 256 + k];
                short8 o;
#pragma unroll
                for (int j = 0; j < 8; ++j) {
                    const float f = fmaxf(fmaf(bf2f((unsigned short)v[j]),
                                               scl[k + j], shl[k + j]), 0.0f);
                    o[j] = (short)f2bf(f);
                }
                *(short8*)&aT[row * 72 + seg * 8] = o;
            } else {
                *(short8*)&aT[row * 72 + seg * 8] =
                    *(const short8*)&hbprev[(size_t)(m0 + row) * 256 + (k - 256)];
            }
        }
        for (int i = tid; i < 1024; i += 256) {
            const int row = i >> 3, seg = i & 7;
            const int k = kc * 64 + seg * 8;
            // local W row -> gate-interleaved global row
            const size_t wr = (size_t)((row >> 5) * 256 + c0h + (row & 31));
            *(short8*)&wT[row * 72 + seg * 8] = (kc < 4)
                ? *(const short8*)&Wihb[wr * 256 + k]
                : *(const short8*)&Whhb[wr * 256 + (k - 256)];
        }
        __syncthreads();
#pragma unroll
        for (int k0 = 0; k0 < 64; k0 += 32) {
            const short8 a = *(const short8*)&aT[(wv * 16 + ml) * 72 + k0 + qk];
#pragma unroll
            for (int ct = 0; ct < 8; ++ct) {
                const short8 b = *(const short8*)&wT[(ct * 16 + ml) * 72 + k0 + qk];
                acc[ct] = __builtin_amdgcn_mfma_f32_16x16x32_bf16(a, b, acc[ct], 0, 0, 0);
            }
        }
    }
    // pointwise LSTM epilogue, fully in registers
#pragma unroll
    for (int hg = 0; hg < 2; ++hg) {
        const int hcol = hg * 16 + ml;
        const float bi = bsum[c0h + hcol];
        const float bf_ = bsum[256 + c0h + hcol];
        const float bg = bsum[512 + c0h + hcol];
        const float bo = bsum[768 + c0h + hcol];
#pragma unroll
        for (int r = 0; r < 4; ++r) {
            const int row = wv * 16 + q * 4 + r;
            const size_t idx = (size_t)(m0 + row) * 256 + c0h + hcol;
            const float gi = acc[hg][r] + bi;
            const float gf = acc[2 + hg][r] + bf_;
            const float gg = acc[4 + hg][r] + bg;
            const float go = acc[6 + hg][r] + bo;
            float c = sigf(gi) * tanhfast(gg);
            if (t > 0) c += sigf(gf) * cst[idx];
            cst[idx] = c;
            hb[idx] = f2bf(sigf(go) * tanhfast(c));
        }
    }
}

// ---------------------------------------------------------------------------
// Stage E: out = bn(h0[:B]) @ W_self1^T + hT @ W_neigh1^T + b1   [4096 x 32]
// 8 rows/block staged once in LDS (BN'd self + hT), then 256 dot products.
// BN rounding matches bn_apply (bf16) -> bit-identical numerics.
// ---------------------------------------------------------------------------
__global__ __launch_bounds__(256) void out_kernel(
    const unsigned short* __restrict__ h0bf, const unsigned short* __restrict__ hTb,
    const float* __restrict__ bn_scale, const float* __restrict__ bn_shift,
    const float* __restrict__ Ws1, const float* __restrict__ Wn1,
    const float* __restrict__ b1, float* __restrict__ out)
{
    __shared__ unsigned short aS[8 * 256];   // BN'd self rows
    __shared__ unsigned short hS[8 * 256];   // hT rows
    __shared__ float scl[256], shl[256];

    const int tid = threadIdx.x;
    const int m0 = blockIdx.x * 8;
    scl[tid] = bn_scale[tid];
    shl[tid] = bn_shift[tid];
    __syncthreads();

    for (int i = tid; i < 512; i += 256) {     // 2 x (8 rows x 32 segs)
        const int sel = i >> 8, idx = i & 255;
        const int row = idx >> 5, seg = idx & 31;
        if (sel == 0) {
            const short8 v = *(const short8*)&h0bf[(size_t)(m0 + row) * 256 + seg * 8];
            short8 o;
#pragma unroll
            for (int j = 0; j < 8; ++j) {
                const float f = fmaxf(fmaf(bf2f((unsigned short)v[j]),
                                           scl[seg * 8 + j], shl[seg * 8 + j]), 0.0f);
                o[j] = (short)f2bf(f);
            }
            *(short8*)&aS[row * 256 + seg * 8] = o;
        } else {
            *(short8*)&hS[row * 256 + seg * 8] =
                *(const short8*)&hTb[(size_t)(m0 + row) * 256 + seg * 8];
        }
    }
    __syncthreads();

    const int row = tid >> 5, cls = tid & 31;
    const float* w0 = Ws1 + (size_t)cls * 256;
    const float* w1 = Wn1 + (size_t)cls * 256;
    const unsigned short* a0 = &aS[row * 256];
    const unsigned short* a1 = &hS[row * 256];
    float s = b1[cls];
#pragma unroll 4
    for (int k8 = 0; k8 < 32; ++k8) {
        const short8 av = *(const short8*)&a0[k8 * 8];
        const short8 bv = *(const short8*)&a1[k8 * 8];
        const float4 wa0 = *(const float4*)&w0[k8 * 8];
        const float4 wa1 = *(const float4*)&w0[k8 * 8 + 4];
        const float4 wb0 = *(const float4*)&w1[k8 * 8];
        const float4 wb1 = *(const float4*)&w1[k8 * 8 + 4];
        s += bf2f((unsigned short)av[0]) * wa0.x + bf2f((unsigned short)av[1]) * wa0.y;
        s += bf2f((unsigned short)av[2]) * wa0.z + bf2f((unsigned short)av[3]) * wa0.w;
        s += bf2f((unsigned short)av[4]) * wa1.x + bf2f((unsigned short)av[5]) * wa1.y;
        s += bf2f((unsigned short)av[6]) * wa1.z + bf2f((unsigned short)av[7]) * wa1.w;
        s += bf2f((unsigned short)bv[0]) * wb0.x + bf2f((unsigned short)bv[1]) * wb0.y;
        s += bf2f((unsigned short)bv[2]) * wb0.z + bf2f((unsigned short)bv[3]) * wb0.w;
        s += bf2f((unsigned short)bv[4]) * wb1.x + bf2f((unsigned short)bv[5]) * wb1.y;
        s += bf2f((unsigned short)bv[6]) * wb1.z + bf2f((unsigned short)bv[7]) * wb1.w;
    }
    out[(size_t)(m0 + row) * 32 + cls] = s;
}

extern "C" void kernel_launch(void* const* d_in, const int* in_sizes, int n_in,
                              void* d_out, int out_size, void* d_ws, size_t ws_size,
                              hipStream_t stream)
{
    const float* x        = (const float*)d_in[0];
    const int*   nbr0     = (const int*)d_in[1];
    const int*   nbr1     = (const int*)d_in[2];
    const float* W_pool   = (const float*)d_in[3];
    const float* b_pool   = (const float*)d_in[4];
    const float* W_self0  = (const float*)d_in[5];
    const float* W_neigh0 = (const float*)d_in[6];
    const float* b0       = (const float*)d_in[7];
    const float* gamma0   = (const float*)d_in[8];
    const float* beta0    = (const float*)d_in[9];
    const float* W_ih     = (const float*)d_in[10];
    const float* W_hh     = (const float*)d_in[11];
    const float* b_ih     = (const float*)d_in[12];
    const float* b_hh     = (const float*)d_in[13];
    const float* W_self1  = (const float*)d_in[14];
    const float* W_neigh1 = (const float*)d_in[15];
    const float* b1       = (const float*)d_in[16];
    float* out = (float*)d_out;

    // ws layout (bytes). h0nbf removed (BN folded into h0bf consumers).
    char* ws = (char*)d_ws;
    unsigned short* h0bf  = (unsigned short*)(ws);               // 20,971,520 B
    unsigned short* hnb   = (unsigned short*)(ws + 20971520);    // 10,485,760 B
    float*          cst   = (float*)(ws + 52428800);             //  4,194,304 B
    unsigned short* hb0   = (unsigned short*)(ws + 56623104);    //  2,097,152 B
    unsigned short* hb1   = (unsigned short*)(ws + 58720256);    //  2,097,152 B
    unsigned short* Wpb   = (unsigned short*)(ws + 60817408);    //     32,768 B
    unsigned short* Ws0b  = (unsigned short*)(ws + 60850176);    //     65,536 B
    unsigned short* Wn0b  = (unsigned short*)(ws + 60915712);    //     65,536 B
    unsigned short* Wihb  = (unsigned short*)(ws + 60981248);    //    524,288 B
    unsigned short* Whhb  = (unsigned short*)(ws + 61505536);    //    524,288 B
    float*          bsum  = (float*)(ws + 62029824);             //      4,096 B
    float*          bn_sum   = (float*)(ws + 62033920);
    float*          bn_sq    = (float*)(ws + 62034944);
    float*          bn_scale = (float*)(ws + 62035968);
    float*          bn_shift = (float*)(ws + 62036992);

    hipMemsetAsync(bn_sum, 0, 2048, stream);        // bn_sum + bn_sq

    cvt_weights_kernel<<<2372, 256, 0, stream>>>(W_pool, W_self0, W_neigh0, W_ih, W_hh,
                                                 b_ih, b_hh, Wpb, Ws0b, Wn0b, Wihb, Whhb, bsum);
    pool_max_kernel<<<N1v / 8, 256, 0, stream>>>(x, nbr0, Wpb, b_pool, hnb);
    h0_kernel<<<dim3(N1v / 64, 2), 256, 0, stream>>>(x, hnb, Ws0b, Wn0b, b0,
                                                     h0bf, bn_sum, bn_sq);
    bn_stats_kernel<<<1, 256, 0, stream>>>(bn_sum, bn_sq, gamma0, beta0, bn_scale, bn_shift);

    for (int t = 0; t < 10; ++t) {
        const unsigned short* hp = (t & 1) ? hb1 : hb0;
        unsigned short*       hn = (t & 1) ? hb0 : hb1;
        lstm_step_kernel<<<dim3(BATCHv / 64, 8), 256, 0, stream>>>(
            h0bf, nbr1, hp, Wihb, Whhb, bsum, bn_scale, bn_shift, cst, hn, t);
    }
    // t=9 wrote hb0 -> final hidden state
    out_kernel<<<BATCHv / 8, 256, 0, stream>>>(h0bf, hb0, bn_scale, bn_shift,
                                               W_self1, W_neigh1, b1, out);
}